// Round 3
// baseline (290.202 us; speedup 1.0000x reference)
//
#include <hip/hip_runtime.h>
#include <math.h>

#define NS 68
#define BLOCK 256
#define WPB 4              // waves per block
#define WAVE 64
#define F4_PER_ROW 17      // 68 / 4
#define HALFW 37           // padded half-tile row stride (36 states max + 1; 37%32=5 -> conflict-light)
#define EPSC 1e-10f

// Structure (round 3):
//  - INPUT: direct per-thread float4 loads of the thread's own row (17 loads,
//    all independent -> one vmcnt wait, 17 KB/wave in flight). Lane-strided
//    (272 B) so per-instruction uncoalesced, but every 64B line is consumed
//    by consecutive k of the same thread -> L1/L2 absorb; HBM traffic unchanged.
//  - COMPUTE: Y[] and d[] fully register-resident (launch_bounds(256,3) gives
//    the allocator ~170 VGPRs; round-2's 92-VGPR cap caused chunked loads).
//  - OUTPUT: coalesced via a HALF-tile per-wave private LDS transpose
//    (64 x 37 f32 = 9.25 KB/wave), two phases: states 0..31 then 32..67.
//    Wave-private + in-order DS pipe -> no barriers anywhere.
__global__ __launch_bounds__(BLOCK, 3) void MAPKPI3KODE_rhs_kernel(
    const float* __restrict__ y,
    const float* __restrict__ params,
    float* __restrict__ out)
{
    __shared__ float sm[WPB * WAVE * HALFW];   // 4*64*37*4 = 37888 B
    const int t    = threadIdx.x;
    const int wid  = t >> 6;
    const int lane = t & 63;
    float* wsm = &sm[wid * WAVE * HALFW];

    const int wave_row0 = (blockIdx.x * WPB + wid) * WAVE;
    const int row = wave_row0 + lane;

    // ---- direct global loads: this thread's whole row, 17 independent float4 ----
    const float4* __restrict__ y4 = (const float4*)y;
    float4 v[F4_PER_ROW];
    #pragma unroll
    for (int k = 0; k < F4_PER_ROW; ++k) v[k] = y4[row * F4_PER_ROW + k];

    float Y[NS];
    #pragma unroll
    for (int k = 0; k < F4_PER_ROW; ++k) {
        Y[4*k+0] = fmaxf(v[k].x, 0.0f);
        Y[4*k+1] = fmaxf(v[k].y, 0.0f);
        Y[4*k+2] = fmaxf(v[k].z, 0.0f);
        Y[4*k+3] = fmaxf(v[k].w, 0.0f);
    }

    // ---- params (uniform; scalar loads) ----
    const float ka1             = params[0];
    const float kr1             = params[1];
    const float kc1             = params[2];
    const float kpCraf          = params[3];
    const float kpMek           = params[4];
    const float kpErk           = params[5];
    const float kDegradEgfr     = params[6];
    const float kErkInbEgfr     = params[7];
    const float kShcDephos      = params[8];
    const float kptpDeg         = params[9];
    const float kGrb2CombShc    = params[10];
    const float kSprtyInbGrb2   = params[11];
    const float kSosCombGrb2    = params[12];
    const float kErkPhosSos     = params[13];
    const float kErkPhosPcraf   = params[14];
    const float kPcrafDegrad    = params[15];
    const float kErkPhosMek     = params[16];
    const float kMekDegrad      = params[17];
    const float kDuspInbErk     = params[18];
    const float kErkDeg         = params[19];
    const float kinbBraf        = params[20];
    const float kDuspStop       = params[21];
    const float kDusps          = params[22];
    const float kSproutyForm    = params[23];
    const float kSprtyComeDown  = params[24];
    const float kdegrad         = params[25];
    // params[26] km_Sprty_decay unused
    const float km_Dusp         = params[27];
    const float km_Sprty        = params[28];
    const float kErkDephos      = params[29];
    const float kDuspDeg        = params[30];
    const float kHer2_act       = params[31];
    const float kHer3_act       = params[32];
    const float k_p85_bind_EGFR = params[33];
    const float k_p85_bind_Her2 = params[34];
    const float k_p85_bind_Her3 = params[35];
    const float k_p85_bind_IGFR = params[36];
    const float k_p85_unbind    = params[37];
    const float k_PI3K_recruit  = params[38];
    const float kMTOR_Feedback  = params[39];
    const float k_PIP2_to_PIP3  = params[40];
    const float k_PTEN          = params[41];
    const float kAkt            = params[42];
    const float kdegradAKT      = params[43];
    const float kb1             = params[44];
    const float k43b1           = params[45];
    const float k4ebp1          = params[46];
    const float k_4EBP1_dephos  = params[47];
    const float kKSRphos        = params[48];
    const float kKSRdephos      = params[49];
    const float kMekByBraf      = params[50];
    const float kMekByCraf      = params[51];
    const float kMekByKSR       = params[52];
    const float Tram            = params[53];
    // params[54] K_tram_RAF unused
    const float K_tram_KSR      = params[55];
    const float n_tram          = params[56];
    const float Vemurafenib     = params[57];
    const float kDimerForm      = params[58];
    const float kDimerDissoc    = params[59];
    const float kParadoxCRAF    = params[60];
    const float IC50_vem        = params[61];
    const float Hill_n_vem      = params[62];
    const float kPDGFR_act      = params[63];
    const float k_p85_bind_PDGFR= params[64];
    const float kS6K_phos       = params[65];
    const float kS6K_dephos     = params[66];
    const float kRAS_PI3K       = params[67];
    const float kERK_IRS_inhibit   = params[68];
    const float kERK_PTEN_activate = params[69];
    const float kAKT_CRAF_inhibit  = params[70];
    const float kS6K_IRS_inhibit   = params[71];
    const float kERK_GAB1_inhibit  = params[72];
    const float kAKT_TSC2_phos     = params[73];
    const float kERK_RSK_activate  = params[74];

    // uniform precomputes
    const float IC50_n   = powf(IC50_vem, Hill_n_vem);
    const float Vem_n    = powf(Vemurafenib, Hill_n_vem);
    const float kBRAF_eff = ka1 * IC50_n / (IC50_n + Vem_n + EPSC);
    const float Ktram_n  = powf(K_tram_KSR, n_tram);
    const float tram_n   = powf(Tram, n_tram);
    const float tram_ksr = Ktram_n / (Ktram_n + tram_n + EPSC);

    float d[NS];

    // --- EGFR / Her2 / Her3 receptor modules ---
    d[0] = -ka1*Y[0] + kr1*Y[1];
    d[1] =  ka1*Y[0] - kr1*Y[1] - kc1*Y[1];
    d[2] =  kc1*Y[1] - kDegradEgfr*Y[2] - kErkInbEgfr*Y[28]*Y[2];
    d[3] = -kHer2_act*Y[3] + kr1*Y[4];
    d[4] =  kHer2_act*Y[3] - kr1*Y[4] - kc1*Y[4];
    d[5] =  kc1*Y[4] - kDegradEgfr*Y[5] - kErkInbEgfr*Y[28]*Y[5];
    d[6] = -kHer3_act*Y[6] + kr1*Y[7];
    d[7] =  kHer3_act*Y[6] - kr1*Y[7] - kc1*Y[7];
    d[8] =  kc1*Y[7] - kDegradEgfr*Y[8] - kErkInbEgfr*Y[28]*Y[8];
    // --- Shc / Grb2 / Sos / Ras ---
    d[9]  = -ka1*Y[2]*Y[9];
    d[10] =  ka1*Y[2]*Y[9] - kShcDephos*Y[11]*Y[10];
    d[11] = -kptpDeg*Y[10]*Y[11];
    d[12] =  kGrb2CombShc*Y[10]*Y[2] - kSprtyInbGrb2*Y[26]*Y[12];
    d[13] =  kSosCombGrb2*Y[12]*Y[10] - kErkPhosSos*Y[24]*Y[13];
    d[14] = -ka1*Y[13]*Y[14];
    d[15] =  ka1*Y[13]*Y[14];
    d[16] = -ka1*Y[13]*Y[16];
    d[17] =  ka1*Y[13]*Y[16];
    d[18] = -ka1*Y[13]*Y[18];
    d[19] =  ka1*Y[13]*Y[18] - ka1*Y[19]*Y[20];
    d[20] = -ka1*Y[19]*Y[20];
    // --- RAF with vemurafenib paradox ---
    {
        const float paradox = kParadoxCRAF * Vemurafenib * Y[61];
        const float akt_inh_craf = kAKT_CRAF_inhibit * Y[52] * Y[21];
        const float dimf = kDimerForm * Y[24] * Y[21] * Vemurafenib;
        const float dimd = kDimerDissoc * Y[61];
        d[21] = -kpCraf*Y[19]*Y[21] + kErkPhosPcraf*Y[28]*Y[22]
                + kPcrafDegrad*Y[22]*Y[35]
                - dimf + dimd - akt_inh_craf;
        d[22] =  kpCraf*Y[19]*Y[21] - kErkPhosPcraf*Y[28]*Y[22]
                - kPcrafDegrad*Y[22]*Y[35] + paradox;
        d[23] = -kBRAF_eff*Y[23]*Y[19] - dimf + dimd;
        d[24] =  kBRAF_eff*Y[23]*Y[19] - kinbBraf*Y[24] - dimf + dimd;
        d[61] =  dimf - dimd - kPcrafDegrad*Y[61]*Y[35];
    }
    // --- MEK / ERK ---
    {
        const float raf_to_mek = kpMek*Y[22] + kMekByBraf*Y[24] + kMekByCraf*Y[22];
        const float ksr_to_mek = kMekByKSR*Y[60];
        const float to_mek = (raf_to_mek + ksr_to_mek) * Y[25];
        d[25] = -to_mek + kErkPhosMek*Y[28]*Y[26] + kMekDegrad*Y[26]*Y[34];
        d[26] =  to_mek - kErkPhosMek*Y[28]*Y[26] - kMekDegrad*Y[26]*Y[34];
        d[27] = -kpErk*Y[26]*Y[27] + kDuspInbErk*Y[30]*Y[28]
                + kErkDeg*Y[28]*Y[33] + kErkDephos*Y[30]*Y[28];
        d[28] =  kpErk*Y[26]*Y[27] - kDuspInbErk*Y[30]*Y[28]
                - kErkDeg*Y[28]*Y[33] - kErkDephos*Y[30]*Y[28];
    }
    // --- DUSP / Sprouty feedback ---
    {
        const float denom_dusp = 1.0f + km_Dusp / (kDusps + EPSC) * Y[28];
        d[29] = km_Dusp*Y[28]/(denom_dusp + EPSC) - kDuspStop*Y[29]*Y[36] - kDuspDeg*Y[29]*Y[28];
        d[30] = -kDuspStop*Y[29]*Y[30];
        const float denom_spry = 1.0f + km_Sprty / (kSproutyForm + EPSC) * Y[28];
        d[31] = km_Sprty*Y[28]/(denom_spry + EPSC) - kSprtyComeDown*Y[31]*Y[32];
        d[32] = -kSprtyComeDown*Y[31]*Y[32];
        d[33] = -kErkDeg*Y[28]*Y[33];
        d[34] = -kMekDegrad*Y[26]*Y[34];
        d[35] = -kPcrafDegrad*Y[22]*Y[35];
        d[36] = -kDuspStop*Y[29]*Y[36];
    }
    // --- IGFR / IRS ---
    d[37] = -ka1*Y[37] + kr1*Y[38];
    d[38] =  ka1*Y[37] - kr1*Y[38] - kc1*Y[38];
    d[39] =  kc1*Y[38] - kErkInbEgfr*Y[28]*Y[39];
    {
        const float erk_irs = kERK_IRS_inhibit*Y[28]*Y[41];
        const float s6k_irs = kS6K_IRS_inhibit*Y[66]*Y[41];
        d[40] = -ka1*Y[2]*Y[40] + erk_irs + s6k_irs;
        d[41] =  ka1*Y[2]*Y[40] - erk_irs - s6k_irs;
    }
    // --- p85 binding ---
    {
        const float gab1 = 1.0f / (1.0f + kERK_GAB1_inhibit*Y[28]);
        const float bE = k_p85_bind_EGFR*Y[2]*Y[42]*gab1;
        const float b2 = k_p85_bind_Her2*Y[5]*Y[42]*gab1;
        const float b3 = k_p85_bind_Her3*Y[8]*Y[42]*gab1;
        const float bI = k_p85_bind_IGFR*Y[39]*Y[42];
        const float bP = k_p85_bind_PDGFR*Y[64]*Y[42];
        const float total_p85c = Y[43] + Y[44] + Y[45] + Y[46] + Y[67];
        d[42] = -bE - b2 - b3 - bI - bP + k_p85_unbind*total_p85c;
        d[43] = bE - k_p85_unbind*Y[43];
        d[44] = b2 - k_p85_unbind*Y[44];
        d[45] = b3 - k_p85_unbind*Y[45];
        d[46] = bI - k_p85_unbind*Y[46];
        d[67] = bP - k_p85_unbind*Y[67];
        // --- PI3K/AKT/mTOR axis ---
        const float pi3k_act = k_PI3K_recruit*total_p85c*Y[47] + kRAS_PI3K*Y[15]*Y[47];
        const float mtor_fb  = kMTOR_Feedback*Y[56]*Y[48];
        d[47] = -pi3k_act + mtor_fb;
        d[48] =  pi3k_act - mtor_fb;
    }
    d[49] = -k_PIP2_to_PIP3*Y[48]*Y[49] + k_PTEN*Y[51]*Y[50];
    d[50] =  k_PIP2_to_PIP3*Y[48]*Y[49] - k_PTEN*Y[51]*Y[50];
    d[51] =  kERK_PTEN_activate*Y[28] - kdegrad*Y[51];
    d[52] =  kAkt*Y[50]*Y[53] - kdegradAKT*Y[52];
    d[53] = -kAkt*Y[50]*Y[53] + kdegradAKT*Y[52];
    d[54] = -kAKT_TSC2_phos*Y[52]*Y[54];
    d[55] =  kAKT_TSC2_phos*Y[52]*Y[54] - kdegrad*Y[55];
    d[56] =  kb1*Y[52]*Y[57] - k43b1*Y[56];
    d[57] = -kb1*Y[52]*Y[57] + k43b1*Y[56];
    d[58] = -k4ebp1*Y[56]*Y[58] + k_4EBP1_dephos*Y[59];
    d[59] =  k4ebp1*Y[56]*Y[58] - k_4EBP1_dephos*Y[59];
    // --- KSR with trametinib hill factor ---
    d[60] =  kKSRphos*Y[19]*Y[62]*tram_ksr - kKSRdephos*Y[60];
    d[62] = -kKSRphos*Y[19]*Y[62]*tram_ksr + kKSRdephos*Y[60];
    // --- PDGFR ---
    d[63] = -kPDGFR_act*Y[63];
    d[64] =  kPDGFR_act*Y[63] - kDegradEgfr*Y[64];
    // --- S6K ---
    d[65] = -kS6K_phos*Y[56]*Y[65] + kS6K_dephos*Y[66] - kERK_RSK_activate*Y[28]*Y[65];
    d[66] =  kS6K_phos*Y[56]*Y[65] - kS6K_dephos*Y[66] + kERK_RSK_activate*Y[28]*Y[65];

    // ================= coalesced store via half-tile LDS (wave-private) =========
    // DS ops execute in program order within a wave, and the compiler cannot
    // reorder may-aliasing LDS accesses -> no barriers, no lgkm hazards.
    float4* __restrict__ out4 = (float4*)out;
    float* my = &wsm[lane * HALFW];

    // --- phase A: states 0..31 (8 float4 per row) ---
    #pragma unroll
    for (int i = 0; i < 32; ++i) my[i] = d[i];
    #pragma unroll
    for (int k = 0; k < 8; ++k) {
        int g = k * WAVE + lane;
        int r = g >> 3;            // 8 float4 per row in phase A
        int c = g & 7;
        const float* src = &wsm[r * HALFW + 4 * c];
        float4 o; o.x = src[0]; o.y = src[1]; o.z = src[2]; o.w = src[3];
        out4[(wave_row0 + r) * F4_PER_ROW + c] = o;
    }

    // --- phase B: states 32..67 (9 float4 per row) ---
    #pragma unroll
    for (int j = 0; j < 36; ++j) my[j] = d[32 + j];
    #pragma unroll
    for (int k = 0; k < 9; ++k) {
        int g = k * WAVE + lane;
        int r = g / 9;
        int c = g - 9 * r;
        const float* src = &wsm[r * HALFW + 4 * c];
        float4 o; o.x = src[0]; o.y = src[1]; o.z = src[2]; o.w = src[3];
        out4[(wave_row0 + r) * F4_PER_ROW + 8 + c] = o;
    }
}

extern "C" void kernel_launch(void* const* d_in, const int* in_sizes, int n_in,
                              void* d_out, int out_size, void* d_ws, size_t ws_size,
                              hipStream_t stream) {
    // setup_inputs order: t (1,), y (B*68,), params (75,)
    const float* y      = (const float*)d_in[1];
    const float* params = (const float*)d_in[2];
    float* out          = (float*)d_out;

    const int rows   = in_sizes[1] / NS;   // B = 524288
    const int blocks = rows / BLOCK;       // 2048 (4 waves x 64 rows per block)

    MAPKPI3KODE_rhs_kernel<<<blocks, BLOCK, 0, stream>>>(y, params, out);
}